// Round 3
// baseline (891.865 us; speedup 1.0000x reference)
//
#include <hip/hip_runtime.h>

#define N_NODES 100000
#define N_EDGES 3200000
#define N_GRAPHS 512
#define IN_CH 50
#define HID 256

typedef unsigned short ushort_t;
using s16x8 = __attribute__((ext_vector_type(8))) short;
using us8   = __attribute__((ext_vector_type(8))) unsigned short;
using f32x4 = __attribute__((ext_vector_type(4))) float;

__device__ __forceinline__ ushort_t f2bf(float f) {
    unsigned int x = __float_as_uint(f);
    unsigned int r = x + 0x7fffu + ((x >> 16) & 1u);
    return (ushort_t)(r >> 16);
}
__device__ __forceinline__ int clampi(int v, int hi) {
    return v < 0 ? 0 : (v >= hi ? hi - 1 : v);
}

// ---- workspace layout (bytes), total ~26.5 MB ----
constexpr size_t OFF_GACC = 0;         // 512*2*4 = 4096
constexpr size_t OFF_GCNT = 4096;      // 512*4   = 2048
constexpr size_t OFF_CTR  = 6144;      // 256
constexpr size_t OFF_DEG  = 6400;      // 100000*4 = 400000
constexpr size_t ZBYTES   = 406400;    // zeroed prefix
constexpr size_t OFF_CUR  = 406528;    // 400000
constexpr size_t OFF_SRC  = 806528;    // 3.2M*4 = 12800000
constexpr size_t OFF_AGG  = 13606528;  // 100000*64*2 = 12800000 (bf16 [N,64])
constexpr size_t OFF_WT   = 26406528;  // 256*128*2 = 65536 -> end 26472064

// K1: degree histogram over dst
__global__ void k_deg(const int* __restrict__ ei, int* __restrict__ deg) {
    int e = blockIdx.x * blockDim.x + threadIdx.x;
    if (e < N_EDGES) {
        int d = clampi(ei[N_EDGES + e], N_NODES);
        atomicAdd(&deg[d], 1);
    }
}

// K2: allocate contiguous (unordered) segments via a single counter
__global__ void k_assign(const int* __restrict__ deg, int* __restrict__ counter,
                         int* __restrict__ cursor) {
    int n = blockIdx.x * blockDim.x + threadIdx.x;
    if (n < N_NODES) cursor[n] = atomicAdd(counter, deg[n]);
}

// K3: place src indices into per-dst segments (cursor ends at start+deg)
__global__ void k_place(const int* __restrict__ ei, int* __restrict__ cursor,
                        int* __restrict__ srcs) {
    int e = blockIdx.x * blockDim.x + threadIdx.x;
    if (e < N_EDGES) {
        int s = clampi(ei[e], N_NODES);
        int d = clampi(ei[N_EDGES + e], N_NODES);
        int pos = atomicAdd(&cursor[d], 1);
        srcs[pos] = s;
    }
}

// K4: combined transposed bf16 weight WT[j][k]: k<50 -> W_l, 64<=k<114 -> W_r, else 0
__global__ void k_buildW(const float* __restrict__ Wl, const float* __restrict__ Wr,
                         ushort_t* __restrict__ WT) {
    int idx = blockIdx.x * blockDim.x + threadIdx.x;   // 0..32767
    int j = idx >> 7;
    int k = idx & 127;
    ushort_t val = 0;
    if (k < IN_CH) val = f2bf(Wl[j * IN_CH + k]);
    else if (k >= 64 && k < 64 + IN_CH) val = f2bf(Wr[j * IN_CH + (k - 64)]);
    WT[idx] = val;
}

// K5: wave-per-node gather mean (fp32 in, bf16 out [N,64], cols 50..63 = 0); graph counts
__global__ void k_gather(const float* __restrict__ x, const int* __restrict__ batch,
                         const int* __restrict__ deg, const int* __restrict__ cursor,
                         const int* __restrict__ srcs, ushort_t* __restrict__ agg,
                         int* __restrict__ gcnt) {
    int gid = (blockIdx.x * blockDim.x + threadIdx.x) >> 6;
    int lane = threadIdx.x & 63;
    if (gid >= N_NODES) return;
    int dg = deg[gid];
    int st = cursor[gid] - dg;   // cursor = start + deg after k_place
    float acc = 0.f;
    int i = 0;
    for (; i + 4 <= dg; i += 4) {
        int s0 = srcs[st + i],     s1 = srcs[st + i + 1];
        int s2 = srcs[st + i + 2], s3 = srcs[st + i + 3];
        if (lane < IN_CH) {
            acc += x[s0 * IN_CH + lane];
            acc += x[s1 * IN_CH + lane];
            acc += x[s2 * IN_CH + lane];
            acc += x[s3 * IN_CH + lane];
        }
    }
    for (; i < dg; i++) {
        int s = srcs[st + i];
        if (lane < IN_CH) acc += x[s * IN_CH + lane];
    }
    float inv = 1.0f / (float)(dg > 1 ? dg : 1);
    ushort_t* ar = agg + (size_t)gid * 64;
    ar[lane] = (lane < IN_CH) ? f2bf(acc * inv) : (ushort_t)0;
    if (lane == 0) atomicAdd(&gcnt[clampi(batch[gid], N_GRAPHS)], 1);
}

// K6: fused MFMA GEMM [N,128]x[128,256] + bias + leaky_relu + W_c proj + graph-sum
// A K-layout: k in [0,50) = agg(bf16), [64,114) = x (converted), else 0 (matches WT)
__global__ __launch_bounds__(256) void k_gemm(const ushort_t* __restrict__ agg,
                                              const float* __restrict__ x,
                                              const ushort_t* __restrict__ WT,
                                              const float* __restrict__ bl,
                                              const float* __restrict__ Wc,
                                              const int* __restrict__ batch,
                                              float* __restrict__ gacc) {
    __shared__ ushort_t Alds[64 * 72];     // 64 rows x 64 k, pad 72
    __shared__ ushort_t Blds[256 * 72];    // 256 hid x 64 k (transposed), pad 72
    __shared__ float ypart[4][64][2];

    const int t = threadIdx.x;
    const int w = t >> 6;          // wave 0..3 -> hid cols [64w, 64w+64)
    const int lane = t & 63;
    const int quad = lane >> 4;
    const int r16 = lane & 15;
    const int row0 = blockIdx.x * 64;

    f32x4 acc[4][4] = {};

    for (int kb = 0; kb < 128; kb += 64) {
        __syncthreads();
        // stage A tile
        {
            int row = t >> 2;
            int cc = (t & 3) << 4;
            int gr = row0 + row;
            ushort_t* dst = &Alds[row * 72 + cc];
            if (kb == 0) {
                if (gr < N_NODES) {
                    const us8* gp = (const us8*)(agg + (size_t)gr * 64 + cc);
                    *(us8*)(dst) = gp[0];
                    *(us8*)(dst + 8) = gp[1];
                } else {
#pragma unroll
                    for (int q = 0; q < 16; q++) dst[q] = 0;
                }
            } else {
                // k = 64 + c maps to x col c (c < 50), else 0
#pragma unroll
                for (int q = 0; q < 16; q++) {
                    int c = cc + q;
                    ushort_t val = 0;
                    if (gr < N_NODES && c < IN_CH) val = f2bf(x[gr * IN_CH + c]);
                    dst[q] = val;
                }
            }
        }
        // stage B tile (WT is [hid][k])
        {
            const us8* gp = (const us8*)(WT + t * 128 + kb);
#pragma unroll
            for (int i = 0; i < 8; i++)
                *(us8*)&Blds[t * 72 + i * 8] = gp[i];
        }
        __syncthreads();
#pragma unroll
        for (int ks = 0; ks < 64; ks += 32) {
            s16x8 af[4], bfr[4];
#pragma unroll
            for (int mi = 0; mi < 4; mi++)
                af[mi] = *(const s16x8*)&Alds[(16 * mi + r16) * 72 + ks + (quad << 3)];
#pragma unroll
            for (int ni = 0; ni < 4; ni++)
                bfr[ni] = *(const s16x8*)&Blds[(w * 64 + 16 * ni + r16) * 72 + ks + (quad << 3)];
#pragma unroll
            for (int mi = 0; mi < 4; mi++)
#pragma unroll
                for (int ni = 0; ni < 4; ni++)
                    acc[mi][ni] = __builtin_amdgcn_mfma_f32_16x16x32_bf16(
                        af[mi], bfr[ni], acc[mi][ni], 0, 0, 0);
        }
    }

    // epilogue: +b_l, leaky_relu, project to 2 classes, reduce over hid
    float blv[4], w0v[4], w1v[4];
#pragma unroll
    for (int ni = 0; ni < 4; ni++) {
        int col = w * 64 + 16 * ni + r16;
        blv[ni] = bl[col];
        w0v[ni] = Wc[col];
        w1v[ni] = Wc[HID + col];
    }
#pragma unroll
    for (int mi = 0; mi < 4; mi++) {
#pragma unroll
        for (int r = 0; r < 4; r++) {
            float p0 = 0.f, p1 = 0.f;
#pragma unroll
            for (int ni = 0; ni < 4; ni++) {
                float h = acc[mi][ni][r] + blv[ni];
                h = (h > 0.f) ? h : 0.01f * h;
                p0 = fmaf(h, w0v[ni], p0);
                p1 = fmaf(h, w1v[ni], p1);
            }
#pragma unroll
            for (int off = 1; off < 16; off <<= 1) {
                p0 += __shfl_xor(p0, off, 16);
                p1 += __shfl_xor(p1, off, 16);
            }
            if (r16 == 0) {
                int rl = 16 * mi + (quad << 2) + r;
                ypart[w][rl][0] = p0;
                ypart[w][rl][1] = p1;
            }
        }
    }
    __syncthreads();
    if (t < 128) {
        int rl = t >> 1, cc = t & 1;
        float s = ypart[0][rl][cc] + ypart[1][rl][cc] + ypart[2][rl][cc] + ypart[3][rl][cc];
        int node = row0 + rl;
        if (node < N_NODES) {
            int g = clampi(batch[node], N_GRAPHS);
            atomicAdd(&gacc[g * 2 + cc], s);
        }
    }
}

// K7: finalize: divide by counts, add b_c, write fp32
__global__ void k_fin(const float* __restrict__ gacc, const int* __restrict__ gcnt,
                      const float* __restrict__ bc, float* __restrict__ out) {
    int t = blockIdx.x * blockDim.x + threadIdx.x;
    if (t < N_GRAPHS * 2) {
        int g = t >> 1, c = t & 1;
        int cnt = gcnt[g];
        out[t] = gacc[t] / (float)(cnt > 1 ? cnt : 1) + bc[c];
    }
}

extern "C" void kernel_launch(void* const* d_in, const int* in_sizes, int n_in,
                              void* d_out, int out_size, void* d_ws, size_t ws_size,
                              hipStream_t stream) {
    const float* x  = (const float*)d_in[0];
    const int* ei   = (const int*)d_in[1];
    const int* batch= (const int*)d_in[2];
    const float* Wl = (const float*)d_in[3];
    const float* bl = (const float*)d_in[4];
    const float* Wr = (const float*)d_in[5];
    const float* Wc = (const float*)d_in[6];
    const float* bc = (const float*)d_in[7];
    float* out = (float*)d_out;

    char* ws = (char*)d_ws;
    float* gacc   = (float*)(ws + OFF_GACC);
    int* gcnt     = (int*)(ws + OFF_GCNT);
    int* counter  = (int*)(ws + OFF_CTR);
    int* deg      = (int*)(ws + OFF_DEG);
    int* cursor   = (int*)(ws + OFF_CUR);
    int* srcs     = (int*)(ws + OFF_SRC);
    ushort_t* agg = (ushort_t*)(ws + OFF_AGG);
    ushort_t* WT  = (ushort_t*)(ws + OFF_WT);

    hipMemsetAsync(ws, 0, ZBYTES, stream);
    k_deg   <<<(N_EDGES + 255) / 256, 256, 0, stream>>>(ei, deg);
    k_assign<<<(N_NODES + 255) / 256, 256, 0, stream>>>(deg, counter, cursor);
    k_place <<<(N_EDGES + 255) / 256, 256, 0, stream>>>(ei, cursor, srcs);
    k_buildW<<<(HID * 128) / 256, 256, 0, stream>>>(Wl, Wr, WT);
    k_gather<<<(N_NODES + 3) / 4, 256, 0, stream>>>(x, batch, deg, cursor, srcs, agg, gcnt);
    k_gemm  <<<(N_NODES + 63) / 64, 256, 0, stream>>>(agg, x, WT, bl, Wc, batch, gacc);
    k_fin   <<<4, 256, 0, stream>>>(gacc, gcnt, bc, out);
}

// Round 4
// 794.933 us; speedup vs baseline: 1.1219x; 1.1219x over previous
//
#include <hip/hip_runtime.h>

#define N_NODES 100000
#define N_EDGES 3200000
#define N_GRAPHS 512
#define IN_CH 50
#define HID 256

typedef unsigned short ushort_t;
using s16x8 = __attribute__((ext_vector_type(8))) short;
using us8   = __attribute__((ext_vector_type(8))) unsigned short;
using us4   = __attribute__((ext_vector_type(4))) unsigned short;
using f32x4 = __attribute__((ext_vector_type(4))) float;

__device__ __forceinline__ float bf2f(ushort_t u) {
    return __uint_as_float(((unsigned int)u) << 16);
}
__device__ __forceinline__ ushort_t f2bf(float f) {
    unsigned int x = __float_as_uint(f);
    unsigned int r = x + 0x7fffu + ((x >> 16) & 1u);
    return (ushort_t)(r >> 16);
}
__device__ __forceinline__ int clampi(int v, int hi) {
    return v < 0 ? 0 : (v >= hi ? hi - 1 : v);
}

// ---- workspace layout (bytes) ----
// Round-3-identical prefix; xb appended (used only if ws_size permits).
constexpr size_t OFF_GACC = 0;         // 512*2*4 = 4096
constexpr size_t OFF_GCNT = 4096;      // 512*4   = 2048
constexpr size_t OFF_CTR  = 6144;      // 256
constexpr size_t OFF_DEG  = 6400;      // 100000*4 = 400000
constexpr size_t ZBYTES   = 406400;    // zeroed prefix
constexpr size_t OFF_CUR  = 406528;    // 400000
constexpr size_t OFF_SRC  = 806528;    // 3.2M*4 = 12800000
constexpr size_t OFF_AGG  = 13606528;  // 100000*64*2 = 12800000 (bf16 [N,64])
constexpr size_t OFF_WT   = 26406528;  // 256*128*2 = 65536
constexpr size_t OFF_XB   = 26472064;  // 100000*64*2 = 12800000 (bf16 [N,64])
constexpr size_t END_FAST = 39272064;

// K1: degree histogram over dst
__global__ void k_deg(const int* __restrict__ ei, int* __restrict__ deg) {
    int e = blockIdx.x * blockDim.x + threadIdx.x;
    if (e < N_EDGES) {
        int d = clampi(ei[N_EDGES + e], N_NODES);
        atomicAdd(&deg[d], 1);
    }
}

// K2: allocate contiguous (unordered) segments via a single counter
__global__ void k_assign(const int* __restrict__ deg, int* __restrict__ counter,
                         int* __restrict__ cursor) {
    int n = blockIdx.x * blockDim.x + threadIdx.x;
    if (n < N_NODES) cursor[n] = atomicAdd(counter, deg[n]);
}

// K3: place src indices into per-dst segments (cursor ends at start+deg)
__global__ void k_place(const int* __restrict__ ei, int* __restrict__ cursor,
                        int* __restrict__ srcs) {
    int e = blockIdx.x * blockDim.x + threadIdx.x;
    if (e < N_EDGES) {
        int s = clampi(ei[e], N_NODES);
        int d = clampi(ei[N_EDGES + e], N_NODES);
        int pos = atomicAdd(&cursor[d], 1);
        srcs[pos] = s;
    }
}

// K4: combined transposed bf16 weight WT[j][k]: k<50 -> W_l, 64<=k<114 -> W_r, else 0
__global__ void k_buildW(const float* __restrict__ Wl, const float* __restrict__ Wr,
                         ushort_t* __restrict__ WT) {
    int idx = blockIdx.x * blockDim.x + threadIdx.x;   // 0..32767
    int j = idx >> 7;
    int k = idx & 127;
    ushort_t val = 0;
    if (k < IN_CH) val = f2bf(Wl[j * IN_CH + k]);
    else if (k >= 64 && k < 64 + IN_CH) val = f2bf(Wr[j * IN_CH + (k - 64)]);
    WT[idx] = val;
}

// K4b: convert x fp32 [N,50] -> xb bf16 [N,64] (cols 50..63 = 0)
__global__ void k_conv(const float* __restrict__ x, ushort_t* __restrict__ xb) {
    int t = blockIdx.x * blockDim.x + threadIdx.x;   // N*64 threads
    if (t < N_NODES * 64) {
        int n = t >> 6, c = t & 63;
        xb[t] = (c < IN_CH) ? f2bf(x[n * IN_CH + c]) : (ushort_t)0;
    }
}

// K5 fast: wave-per-node gather mean from bf16 xb; quad-per-row, ushort4/lane.
__global__ void k_gather_bf(const ushort_t* __restrict__ xb, const int* __restrict__ batch,
                            const int* __restrict__ deg, const int* __restrict__ cursor,
                            const int* __restrict__ srcs, ushort_t* __restrict__ agg,
                            int* __restrict__ gcnt) {
    int gid = (blockIdx.x * blockDim.x + threadIdx.x) >> 6;
    int lane = threadIdx.x & 63;
    if (gid >= N_NODES) return;
    int q = lane >> 4;          // quad 0..3 -> which src row in group of 4
    int c16 = lane & 15;        // channels [4*c16, 4*c16+4)
    int dg = deg[gid];
    int st = cursor[gid] - dg;  // cursor = start + deg after k_place
    float a0 = 0.f, a1 = 0.f, a2 = 0.f, a3 = 0.f;
    int i = 0;
    for (; i + 4 <= dg; i += 4) {
        int s = srcs[st + i + q];
        us4 v = *(const us4*)(xb + (size_t)s * 64 + (c16 << 2));
        a0 += bf2f(v.x); a1 += bf2f(v.y); a2 += bf2f(v.z); a3 += bf2f(v.w);
    }
    int rem = dg - i;
    if (q < rem) {
        int s = srcs[st + i + q];
        us4 v = *(const us4*)(xb + (size_t)s * 64 + (c16 << 2));
        a0 += bf2f(v.x); a1 += bf2f(v.y); a2 += bf2f(v.z); a3 += bf2f(v.w);
    }
    // cross-quad reduce (quads hold disjoint src partials of same node)
    a0 += __shfl_xor(a0, 16); a1 += __shfl_xor(a1, 16);
    a2 += __shfl_xor(a2, 16); a3 += __shfl_xor(a3, 16);
    a0 += __shfl_xor(a0, 32); a1 += __shfl_xor(a1, 32);
    a2 += __shfl_xor(a2, 32); a3 += __shfl_xor(a3, 32);
    float inv = 1.0f / (float)(dg > 1 ? dg : 1);
    if (q == 0) {
        us4 o;
        o.x = f2bf(a0 * inv); o.y = f2bf(a1 * inv);
        o.z = f2bf(a2 * inv); o.w = f2bf(a3 * inv);
        *(us4*)(agg + (size_t)gid * 64 + (c16 << 2)) = o;
    }
    if (lane == 0) atomicAdd(&gcnt[clampi(batch[gid], N_GRAPHS)], 1);
}

// K5 fallback: round-3 fp32 gather (used if ws_size too small for xb)
__global__ void k_gather_f32(const float* __restrict__ x, const int* __restrict__ batch,
                             const int* __restrict__ deg, const int* __restrict__ cursor,
                             const int* __restrict__ srcs, ushort_t* __restrict__ agg,
                             int* __restrict__ gcnt) {
    int gid = (blockIdx.x * blockDim.x + threadIdx.x) >> 6;
    int lane = threadIdx.x & 63;
    if (gid >= N_NODES) return;
    int dg = deg[gid];
    int st = cursor[gid] - dg;
    float acc = 0.f;
    int i = 0;
    for (; i + 4 <= dg; i += 4) {
        int s0 = srcs[st + i],     s1 = srcs[st + i + 1];
        int s2 = srcs[st + i + 2], s3 = srcs[st + i + 3];
        if (lane < IN_CH) {
            acc += x[s0 * IN_CH + lane];
            acc += x[s1 * IN_CH + lane];
            acc += x[s2 * IN_CH + lane];
            acc += x[s3 * IN_CH + lane];
        }
    }
    for (; i < dg; i++) {
        int s = srcs[st + i];
        if (lane < IN_CH) acc += x[s * IN_CH + lane];
    }
    float inv = 1.0f / (float)(dg > 1 ? dg : 1);
    ushort_t* ar = agg + (size_t)gid * 64;
    ar[lane] = (lane < IN_CH) ? f2bf(acc * inv) : (ushort_t)0;
    if (lane == 0) atomicAdd(&gcnt[clampi(batch[gid], N_GRAPHS)], 1);
}

// K6: fused MFMA GEMM [N,128]x[128,256] + bias + leaky_relu + W_c proj + graph-sum
// A K-layout: k in [0,50) = agg(bf16), [64,114) = x, else 0 (matches WT)
// xb (optional, may be null): bf16 copy of x for vectorized kb=64 staging.
__global__ __launch_bounds__(256) void k_gemm(const ushort_t* __restrict__ agg,
                                              const float* __restrict__ x,
                                              const ushort_t* __restrict__ xb,
                                              const ushort_t* __restrict__ WT,
                                              const float* __restrict__ bl,
                                              const float* __restrict__ Wc,
                                              const int* __restrict__ batch,
                                              float* __restrict__ gacc) {
    __shared__ ushort_t Alds[64 * 72];     // 64 rows x 64 k, pad 72
    __shared__ ushort_t Blds[256 * 72];    // 256 hid x 64 k (transposed), pad 72
    __shared__ float ypart[4][64][2];

    const int t = threadIdx.x;
    const int w = t >> 6;
    const int lane = t & 63;
    const int quad = lane >> 4;
    const int r16 = lane & 15;
    const int row0 = blockIdx.x * 64;

    f32x4 acc[4][4] = {};

    for (int kb = 0; kb < 128; kb += 64) {
        __syncthreads();
        // stage A tile
        {
            int row = t >> 2;
            int cc = (t & 3) << 4;
            int gr = row0 + row;
            ushort_t* dst = &Alds[row * 72 + cc];
            if (kb == 0) {
                if (gr < N_NODES) {
                    const us8* gp = (const us8*)(agg + (size_t)gr * 64 + cc);
                    *(us8*)(dst) = gp[0];
                    *(us8*)(dst + 8) = gp[1];
                } else {
#pragma unroll
                    for (int q = 0; q < 16; q++) dst[q] = 0;
                }
            } else if (xb != nullptr) {
                if (gr < N_NODES) {
                    const us8* gp = (const us8*)(xb + (size_t)gr * 64 + cc);
                    *(us8*)(dst) = gp[0];
                    *(us8*)(dst + 8) = gp[1];
                } else {
#pragma unroll
                    for (int q = 0; q < 16; q++) dst[q] = 0;
                }
            } else {
#pragma unroll
                for (int q = 0; q < 16; q++) {
                    int c = cc + q;
                    ushort_t val = 0;
                    if (gr < N_NODES && c < IN_CH) val = f2bf(x[gr * IN_CH + c]);
                    dst[q] = val;
                }
            }
        }
        // stage B tile (WT is [hid][k])
        {
            const us8* gp = (const us8*)(WT + t * 128 + kb);
#pragma unroll
            for (int i = 0; i < 8; i++)
                *(us8*)&Blds[t * 72 + i * 8] = gp[i];
        }
        __syncthreads();
#pragma unroll
        for (int ks = 0; ks < 64; ks += 32) {
            s16x8 af[4], bfr[4];
#pragma unroll
            for (int mi = 0; mi < 4; mi++)
                af[mi] = *(const s16x8*)&Alds[(16 * mi + r16) * 72 + ks + (quad << 3)];
#pragma unroll
            for (int ni = 0; ni < 4; ni++)
                bfr[ni] = *(const s16x8*)&Blds[(w * 64 + 16 * ni + r16) * 72 + ks + (quad << 3)];
#pragma unroll
            for (int mi = 0; mi < 4; mi++)
#pragma unroll
                for (int ni = 0; ni < 4; ni++)
                    acc[mi][ni] = __builtin_amdgcn_mfma_f32_16x16x32_bf16(
                        af[mi], bfr[ni], acc[mi][ni], 0, 0, 0);
        }
    }

    // epilogue: +b_l, leaky_relu, project to 2 classes, reduce over hid
    float blv[4], w0v[4], w1v[4];
#pragma unroll
    for (int ni = 0; ni < 4; ni++) {
        int col = w * 64 + 16 * ni + r16;
        blv[ni] = bl[col];
        w0v[ni] = Wc[col];
        w1v[ni] = Wc[HID + col];
    }
#pragma unroll
    for (int mi = 0; mi < 4; mi++) {
#pragma unroll
        for (int r = 0; r < 4; r++) {
            float p0 = 0.f, p1 = 0.f;
#pragma unroll
            for (int ni = 0; ni < 4; ni++) {
                float h = acc[mi][ni][r] + blv[ni];
                h = (h > 0.f) ? h : 0.01f * h;
                p0 = fmaf(h, w0v[ni], p0);
                p1 = fmaf(h, w1v[ni], p1);
            }
#pragma unroll
            for (int off = 1; off < 16; off <<= 1) {
                p0 += __shfl_xor(p0, off, 16);
                p1 += __shfl_xor(p1, off, 16);
            }
            if (r16 == 0) {
                int rl = 16 * mi + (quad << 2) + r;
                ypart[w][rl][0] = p0;
                ypart[w][rl][1] = p1;
            }
        }
    }
    __syncthreads();
    if (t < 128) {
        int rl = t >> 1, cc = t & 1;
        float s = ypart[0][rl][cc] + ypart[1][rl][cc] + ypart[2][rl][cc] + ypart[3][rl][cc];
        int node = row0 + rl;
        if (node < N_NODES) {
            int g = clampi(batch[node], N_GRAPHS);
            atomicAdd(&gacc[g * 2 + cc], s);
        }
    }
}

// K7: finalize: divide by counts, add b_c, write fp32
__global__ void k_fin(const float* __restrict__ gacc, const int* __restrict__ gcnt,
                      const float* __restrict__ bc, float* __restrict__ out) {
    int t = blockIdx.x * blockDim.x + threadIdx.x;
    if (t < N_GRAPHS * 2) {
        int g = t >> 1, c = t & 1;
        int cnt = gcnt[g];
        out[t] = gacc[t] / (float)(cnt > 1 ? cnt : 1) + bc[c];
    }
}

extern "C" void kernel_launch(void* const* d_in, const int* in_sizes, int n_in,
                              void* d_out, int out_size, void* d_ws, size_t ws_size,
                              hipStream_t stream) {
    const float* x  = (const float*)d_in[0];
    const int* ei   = (const int*)d_in[1];
    const int* batch= (const int*)d_in[2];
    const float* Wl = (const float*)d_in[3];
    const float* bl = (const float*)d_in[4];
    const float* Wr = (const float*)d_in[5];
    const float* Wc = (const float*)d_in[6];
    const float* bc = (const float*)d_in[7];
    float* out = (float*)d_out;

    char* ws = (char*)d_ws;
    float* gacc   = (float*)(ws + OFF_GACC);
    int* gcnt     = (int*)(ws + OFF_GCNT);
    int* counter  = (int*)(ws + OFF_CTR);
    int* deg      = (int*)(ws + OFF_DEG);
    int* cursor   = (int*)(ws + OFF_CUR);
    int* srcs     = (int*)(ws + OFF_SRC);
    ushort_t* agg = (ushort_t*)(ws + OFF_AGG);
    ushort_t* WT  = (ushort_t*)(ws + OFF_WT);
    const bool fast = (ws_size >= END_FAST);
    ushort_t* xb  = fast ? (ushort_t*)(ws + OFF_XB) : nullptr;

    hipMemsetAsync(ws, 0, ZBYTES, stream);
    k_deg   <<<(N_EDGES + 255) / 256, 256, 0, stream>>>(ei, deg);
    k_assign<<<(N_NODES + 255) / 256, 256, 0, stream>>>(deg, counter, cursor);
    k_place <<<(N_EDGES + 255) / 256, 256, 0, stream>>>(ei, cursor, srcs);
    k_buildW<<<(HID * 128) / 256, 256, 0, stream>>>(Wl, Wr, WT);
    if (fast) {
        k_conv<<<(N_NODES * 64 + 255) / 256, 256, 0, stream>>>(x, xb);
        k_gather_bf<<<(N_NODES + 3) / 4, 256, 0, stream>>>(xb, batch, deg, cursor, srcs, agg, gcnt);
    } else {
        k_gather_f32<<<(N_NODES + 3) / 4, 256, 0, stream>>>(x, batch, deg, cursor, srcs, agg, gcnt);
    }
    k_gemm<<<(N_NODES + 63) / 64, 256, 0, stream>>>(agg, x, xb, WT, bl, Wc, batch, gacc);
    k_fin <<<4, 256, 0, stream>>>(gacc, gcnt, bc, out);
}

// Round 5
// 497.410 us; speedup vs baseline: 1.7930x; 1.5981x over previous
//
#include <hip/hip_runtime.h>

#define N_NODES 100000
#define N_EDGES 3200000
#define N_GRAPHS 512
#define IN_CH 50
#define HID 256
#define NB 391          // buckets of 256 nodes
#define NBLK 196        // edge blocks
#define EPB 16384       // edges per block

typedef unsigned short ushort_t;
using s16x8 = __attribute__((ext_vector_type(8))) short;
using us8   = __attribute__((ext_vector_type(8))) unsigned short;
using us4   = __attribute__((ext_vector_type(4))) unsigned short;
using f32x4 = __attribute__((ext_vector_type(4))) float;

__device__ __forceinline__ float bf2f(ushort_t u) {
    return __uint_as_float(((unsigned int)u) << 16);
}
__device__ __forceinline__ ushort_t f2bf(float f) {
    unsigned int x = __float_as_uint(f);
    unsigned int r = x + 0x7fffu + ((x >> 16) & 1u);
    return (ushort_t)(r >> 16);
}
__device__ __forceinline__ int clampi(int v, int hi) {
    return v < 0 ? 0 : (v >= hi ? hi - 1 : v);
}

// ---- workspace layout (bytes), total 39,027,072 (proven ws_size >= 39,272,064) ----
constexpr size_t OFF_GACC   = 0;          // 512*2*4 = 4096
constexpr size_t OFF_GCNT   = 4096;       // 512*4   = 2048
constexpr size_t OFF_BASE   = 6144;       // (NB+1)*4 = 1568, pad to 8192
constexpr size_t ZBYTES     = 8192;       // zeroed prefix (gacc, gcnt; base overwritten anyway)
constexpr size_t OFF_COUNTS = 8192;       // u16 [NBLK][NB] = 153272, pad -> 161536
constexpr size_t OFF_SD     = 161536;     // packed (start<<10|deg) u32 [N] = 400000
constexpr size_t OFF_SRC    = 561536;     // int [E] = 12.8MB
constexpr size_t OFF_XB     = 13361536;   // bf16 [N,64] = 12.8MB
constexpr size_t OFF_EP     = 26161536;   // epairs int [E] = 12.8MB; agg bf16 [N,64] overlays after k_csr
constexpr size_t OFF_WT     = 38961536;   // bf16 [256][128] = 65536 -> end 39,027,072

// P1: per-(block,bucket) edge counts via LDS histogram
__global__ __launch_bounds__(256) void k_count(const int* __restrict__ ei,
                                               ushort_t* __restrict__ counts) {
    __shared__ int h[NB];
    int blk = blockIdx.x, t = threadIdx.x;
    for (int i = t; i < NB; i += 256) h[i] = 0;
    __syncthreads();
    int e0 = blk * EPB;
    for (int i = 0; i < EPB; i += 256) {
        int e = e0 + i + t;
        if (e < N_EDGES) {
            int d = clampi(ei[N_EDGES + e], N_NODES);
            atomicAdd(&h[d >> 8], 1);
        }
    }
    __syncthreads();
    for (int i = t; i < NB; i += 256) counts[blk * NB + i] = (ushort_t)h[i];
}

// P2a: per-bucket column scan: counts[blk][b] -> exclusive prefix; base[b] = column total
__global__ __launch_bounds__(256) void k_scan_col(ushort_t* __restrict__ counts,
                                                  int* __restrict__ base) {
    __shared__ int a[256];
    __shared__ int orig[256];
    int b = blockIdx.x, t = threadIdx.x;
    int v = (t < NBLK) ? (int)counts[t * NB + b] : 0;
    orig[t] = v; a[t] = v;
    __syncthreads();
    for (int off = 1; off < 256; off <<= 1) {
        int u = (t >= off) ? a[t - off] : 0;
        __syncthreads();
        a[t] += u;
        __syncthreads();
    }
    if (t < NBLK) counts[t * NB + b] = (ushort_t)(a[t] - orig[t]);
    if (t == 255) base[b] = a[255];
}

// P2b: exclusive scan over bucket totals -> base[b]; base[NB] = total
__global__ __launch_bounds__(512) void k_scan_bucket(int* __restrict__ base) {
    __shared__ int a[512];
    __shared__ int orig[512];
    int t = threadIdx.x;
    int v = (t < NB) ? base[t] : 0;
    orig[t] = v; a[t] = v;
    __syncthreads();
    for (int off = 1; off < 512; off <<= 1) {
        int u = (t >= off) ? a[t - off] : 0;
        __syncthreads();
        a[t] += u;
        __syncthreads();
    }
    if (t < NB) base[t] = a[t] - orig[t];
    if (t == NB - 1) base[NB] = a[t];
}

// P3: scatter edges into bucket-contiguous runs; pack (src<<8)|dst_local
__global__ __launch_bounds__(256) void k_scatter(const int* __restrict__ ei,
                                                 const ushort_t* __restrict__ counts,
                                                 const int* __restrict__ base,
                                                 int* __restrict__ ep) {
    __shared__ int rnk[NB];
    __shared__ int ob[NB];
    int blk = blockIdx.x, t = threadIdx.x;
    for (int i = t; i < NB; i += 256) {
        rnk[i] = 0;
        ob[i] = base[i] + (int)counts[blk * NB + i];
    }
    __syncthreads();
    int e0 = blk * EPB;
    for (int i = 0; i < EPB; i += 256) {
        int e = e0 + i + t;
        if (e < N_EDGES) {
            int s = clampi(ei[e], N_NODES);
            int d = clampi(ei[N_EDGES + e], N_NODES);
            int b = d >> 8;
            int r = atomicAdd(&rnk[b], 1);
            ep[ob[b] + r] = (s << 8) | (d & 255);
        }
    }
}

// P4: per-bucket fine CSR: deg histogram -> scan -> place; emit packed start|deg
__global__ __launch_bounds__(256) void k_csr(const int* __restrict__ ep,
                                             const int* __restrict__ base,
                                             int* __restrict__ srcs,
                                             unsigned int* __restrict__ sd) {
    __shared__ int ldeg[256];
    __shared__ int a[256];
    __shared__ int lcur[256];
    int b = blockIdx.x, t = threadIdx.x;
    int e0 = base[b], e1 = base[b + 1];
    ldeg[t] = 0;
    __syncthreads();
    for (int e = e0 + t; e < e1; e += 256) atomicAdd(&ldeg[ep[e] & 255], 1);
    __syncthreads();
    a[t] = ldeg[t];
    __syncthreads();
    for (int off = 1; off < 256; off <<= 1) {
        int u = (t >= off) ? a[t - off] : 0;
        __syncthreads();
        a[t] += u;
        __syncthreads();
    }
    int excl = a[t] - ldeg[t];
    lcur[t] = excl;
    __syncthreads();
    int n = (b << 8) + t;
    if (n < N_NODES) {
        int dgc = ldeg[t] < 1023 ? ldeg[t] : 1023;
        sd[n] = ((unsigned int)(e0 + excl) << 10) | (unsigned int)dgc;
    }
    for (int e = e0 + t; e < e1; e += 256) {
        int p = ep[e];
        int dl = p & 255;
        int r = atomicAdd(&lcur[dl], 1);
        srcs[e0 + r] = p >> 8;
    }
}

// K4: combined transposed bf16 weight WT[j][k]: k<50 -> W_l, 64<=k<114 -> W_r, else 0
__global__ void k_buildW(const float* __restrict__ Wl, const float* __restrict__ Wr,
                         ushort_t* __restrict__ WT) {
    int idx = blockIdx.x * blockDim.x + threadIdx.x;
    int j = idx >> 7;
    int k = idx & 127;
    ushort_t val = 0;
    if (k < IN_CH) val = f2bf(Wl[j * IN_CH + k]);
    else if (k >= 64 && k < 64 + IN_CH) val = f2bf(Wr[j * IN_CH + (k - 64)]);
    WT[idx] = val;
}

// K4b: convert x fp32 [N,50] -> xb bf16 [N,64] (cols 50..63 = 0)
__global__ void k_conv(const float* __restrict__ x, ushort_t* __restrict__ xb) {
    int t = blockIdx.x * blockDim.x + threadIdx.x;
    if (t < N_NODES * 64) {
        int n = t >> 6, c = t & 63;
        xb[t] = (c < IN_CH) ? f2bf(x[n * IN_CH + c]) : (ushort_t)0;
    }
}

// K5: wave-per-node gather mean from bf16 xb; quad-per-row, ushort4/lane
__global__ void k_gather_bf(const ushort_t* __restrict__ xb, const int* __restrict__ batch,
                            const unsigned int* __restrict__ sd,
                            const int* __restrict__ srcs, ushort_t* __restrict__ agg,
                            int* __restrict__ gcnt) {
    int gid = (blockIdx.x * blockDim.x + threadIdx.x) >> 6;
    int lane = threadIdx.x & 63;
    if (gid >= N_NODES) return;
    int q = lane >> 4;
    int c16 = lane & 15;
    unsigned int v = sd[gid];
    int dg = (int)(v & 1023u);
    int st = (int)(v >> 10);
    float a0 = 0.f, a1 = 0.f, a2 = 0.f, a3 = 0.f;
    int i = 0;
    for (; i + 4 <= dg; i += 4) {
        int s = srcs[st + i + q];
        us4 w = *(const us4*)(xb + (size_t)s * 64 + (c16 << 2));
        a0 += bf2f(w.x); a1 += bf2f(w.y); a2 += bf2f(w.z); a3 += bf2f(w.w);
    }
    int rem = dg - i;
    if (q < rem) {
        int s = srcs[st + i + q];
        us4 w = *(const us4*)(xb + (size_t)s * 64 + (c16 << 2));
        a0 += bf2f(w.x); a1 += bf2f(w.y); a2 += bf2f(w.z); a3 += bf2f(w.w);
    }
    a0 += __shfl_xor(a0, 16); a1 += __shfl_xor(a1, 16);
    a2 += __shfl_xor(a2, 16); a3 += __shfl_xor(a3, 16);
    a0 += __shfl_xor(a0, 32); a1 += __shfl_xor(a1, 32);
    a2 += __shfl_xor(a2, 32); a3 += __shfl_xor(a3, 32);
    float inv = 1.0f / (float)(dg > 1 ? dg : 1);
    if (q == 0) {
        us4 o;
        o.x = f2bf(a0 * inv); o.y = f2bf(a1 * inv);
        o.z = f2bf(a2 * inv); o.w = f2bf(a3 * inv);
        *(us4*)(agg + (size_t)gid * 64 + (c16 << 2)) = o;
    }
    if (lane == 0) atomicAdd(&gcnt[clampi(batch[gid], N_GRAPHS)], 1);
}

// K6: fused MFMA GEMM [N,128]x[128,256] + bias + leaky_relu + W_c proj + graph-sum
__global__ __launch_bounds__(256) void k_gemm(const ushort_t* __restrict__ agg,
                                              const ushort_t* __restrict__ xb,
                                              const ushort_t* __restrict__ WT,
                                              const float* __restrict__ bl,
                                              const float* __restrict__ Wc,
                                              const int* __restrict__ batch,
                                              float* __restrict__ gacc) {
    __shared__ ushort_t Alds[64 * 72];
    __shared__ ushort_t Blds[256 * 72];
    __shared__ float ypart[4][64][2];

    const int t = threadIdx.x;
    const int w = t >> 6;
    const int lane = t & 63;
    const int quad = lane >> 4;
    const int r16 = lane & 15;
    const int row0 = blockIdx.x * 64;

    f32x4 acc[4][4] = {};

    for (int kb = 0; kb < 128; kb += 64) {
        __syncthreads();
        {
            int row = t >> 2;
            int cc = (t & 3) << 4;
            int gr = row0 + row;
            ushort_t* dst = &Alds[row * 72 + cc];
            const ushort_t* srcp = (kb == 0) ? agg : xb;
            if (gr < N_NODES) {
                const us8* gp = (const us8*)(srcp + (size_t)gr * 64 + cc);
                *(us8*)(dst) = gp[0];
                *(us8*)(dst + 8) = gp[1];
            } else {
#pragma unroll
                for (int qq = 0; qq < 16; qq++) dst[qq] = 0;
            }
        }
        {
            const us8* gp = (const us8*)(WT + t * 128 + kb);
#pragma unroll
            for (int i = 0; i < 8; i++)
                *(us8*)&Blds[t * 72 + i * 8] = gp[i];
        }
        __syncthreads();
#pragma unroll
        for (int ks = 0; ks < 64; ks += 32) {
            s16x8 af[4], bfr[4];
#pragma unroll
            for (int mi = 0; mi < 4; mi++)
                af[mi] = *(const s16x8*)&Alds[(16 * mi + r16) * 72 + ks + (quad << 3)];
#pragma unroll
            for (int ni = 0; ni < 4; ni++)
                bfr[ni] = *(const s16x8*)&Blds[(w * 64 + 16 * ni + r16) * 72 + ks + (quad << 3)];
#pragma unroll
            for (int mi = 0; mi < 4; mi++)
#pragma unroll
                for (int ni = 0; ni < 4; ni++)
                    acc[mi][ni] = __builtin_amdgcn_mfma_f32_16x16x32_bf16(
                        af[mi], bfr[ni], acc[mi][ni], 0, 0, 0);
        }
    }

    float blv[4], w0v[4], w1v[4];
#pragma unroll
    for (int ni = 0; ni < 4; ni++) {
        int col = w * 64 + 16 * ni + r16;
        blv[ni] = bl[col];
        w0v[ni] = Wc[col];
        w1v[ni] = Wc[HID + col];
    }
#pragma unroll
    for (int mi = 0; mi < 4; mi++) {
#pragma unroll
        for (int r = 0; r < 4; r++) {
            float p0 = 0.f, p1 = 0.f;
#pragma unroll
            for (int ni = 0; ni < 4; ni++) {
                float h = acc[mi][ni][r] + blv[ni];
                h = (h > 0.f) ? h : 0.01f * h;
                p0 = fmaf(h, w0v[ni], p0);
                p1 = fmaf(h, w1v[ni], p1);
            }
#pragma unroll
            for (int off = 1; off < 16; off <<= 1) {
                p0 += __shfl_xor(p0, off, 16);
                p1 += __shfl_xor(p1, off, 16);
            }
            if (r16 == 0) {
                int rl = 16 * mi + (quad << 2) + r;
                ypart[w][rl][0] = p0;
                ypart[w][rl][1] = p1;
            }
        }
    }
    __syncthreads();
    if (t < 128) {
        int rl = t >> 1, cc = t & 1;
        float s = ypart[0][rl][cc] + ypart[1][rl][cc] + ypart[2][rl][cc] + ypart[3][rl][cc];
        int node = row0 + rl;
        if (node < N_NODES) {
            int g = clampi(batch[node], N_GRAPHS);
            atomicAdd(&gacc[g * 2 + cc], s);
        }
    }
}

// K7: finalize
__global__ void k_fin(const float* __restrict__ gacc, const int* __restrict__ gcnt,
                      const float* __restrict__ bc, float* __restrict__ out) {
    int t = blockIdx.x * blockDim.x + threadIdx.x;
    if (t < N_GRAPHS * 2) {
        int g = t >> 1, c = t & 1;
        int cnt = gcnt[g];
        out[t] = gacc[t] / (float)(cnt > 1 ? cnt : 1) + bc[c];
    }
}

extern "C" void kernel_launch(void* const* d_in, const int* in_sizes, int n_in,
                              void* d_out, int out_size, void* d_ws, size_t ws_size,
                              hipStream_t stream) {
    const float* x  = (const float*)d_in[0];
    const int* ei   = (const int*)d_in[1];
    const int* batch= (const int*)d_in[2];
    const float* Wl = (const float*)d_in[3];
    const float* bl = (const float*)d_in[4];
    const float* Wr = (const float*)d_in[5];
    const float* Wc = (const float*)d_in[6];
    const float* bc = (const float*)d_in[7];
    float* out = (float*)d_out;

    char* ws = (char*)d_ws;
    float* gacc       = (float*)(ws + OFF_GACC);
    int* gcnt         = (int*)(ws + OFF_GCNT);
    int* base         = (int*)(ws + OFF_BASE);
    ushort_t* counts  = (ushort_t*)(ws + OFF_COUNTS);
    unsigned int* sd  = (unsigned int*)(ws + OFF_SD);
    int* srcs         = (int*)(ws + OFF_SRC);
    ushort_t* xb      = (ushort_t*)(ws + OFF_XB);
    int* ep           = (int*)(ws + OFF_EP);
    ushort_t* agg     = (ushort_t*)(ws + OFF_EP);   // overlays dead ep
    ushort_t* WT      = (ushort_t*)(ws + OFF_WT);

    hipMemsetAsync(ws, 0, ZBYTES, stream);
    k_count      <<<NBLK, 256, 0, stream>>>(ei, counts);
    k_scan_col   <<<NB, 256, 0, stream>>>(counts, base);
    k_scan_bucket<<<1, 512, 0, stream>>>(base);
    k_scatter    <<<NBLK, 256, 0, stream>>>(ei, counts, base, ep);
    k_csr        <<<NB, 256, 0, stream>>>(ep, base, srcs, sd);
    k_buildW     <<<(HID * 128) / 256, 256, 0, stream>>>(Wl, Wr, WT);
    k_conv       <<<(N_NODES * 64 + 255) / 256, 256, 0, stream>>>(x, xb);
    k_gather_bf  <<<(N_NODES + 3) / 4, 256, 0, stream>>>(xb, batch, sd, srcs, agg, gcnt);
    k_gemm       <<<(N_NODES + 63) / 64, 256, 0, stream>>>(agg, xb, WT, bl, Wc, batch, gacc);
    k_fin        <<<4, 256, 0, stream>>>(gacc, gcnt, bc, out);
}